// Round 10
// baseline (63.247 us; speedup 1.0000x reference)
//
#include <hip/hip_runtime.h>
#include <math.h>

constexpr int N = 4096;
constexpr int D = 256;
constexpr int ND = N * D;
constexpr int KMAX = 32;             // safe bound on directed degree (Poisson(~6))
constexpr int ROW_BLOCKS = N / 4;    // 4 waves (rows) per 256-thread block
constexpr int RPB = 16;              // rows per prep block
constexpr int PREP_BLOCKS = N / RPB; // 256

// ---- bf16 helpers (RNE) ----
__device__ inline unsigned short f2bf(float f) {
    unsigned u = __float_as_uint(f);
    unsigned r = (u + 0x7FFFu + ((u >> 16) & 1u)) >> 16;
    return (unsigned short)r;
}
__device__ inline float bf2f(unsigned short h) {
    return __uint_as_float(((unsigned)h) << 16);
}
__device__ inline float4 bf4_to_f4(ushort4 s) {
    return make_float4(bf2f(s.x), bf2f(s.y), bf2f(s.z), bf2f(s.w));
}
__device__ inline ushort4 f4_to_bf4(float4 f) {
    ushort4 s; s.x = f2bf(f.x); s.y = f2bf(f.y); s.z = f2bf(f.z); s.w = f2bf(f.w);
    return s;
}

__device__ inline int lower_bound(const int* __restrict__ a, int n, int key) {
    int lo = 0, hi = n;
    while (lo < hi) {
        int mid = (lo + hi) >> 1;
        if (a[mid] < key) lo = mid + 1; else hi = mid;
    }
    return lo;
}

// ---------------- K1: fused prep ----------------
// Block b owns rows [16b,16b+16): LDS deg counters + full-edge-list scan (L2-hot)
// -> no cross-block atomic hazard, so zero+build fuse. Also: X->bf16 cast and
// segment-bound binary searches (grid-strided, independent).
__global__ __launch_bounds__(256) void k_prep(const int* __restrict__ row,
                                              const int* __restrict__ col, int nnz_e,
                                              const float* __restrict__ X,
                                              unsigned short* __restrict__ Xbf,
                                              int* __restrict__ deg, int* __restrict__ ell,
                                              const int* __restrict__ comm_ids, int M, int C,
                                              int* __restrict__ start,
                                              const int* __restrict__ comm_owner,
                                              int* __restrict__ ostart) {
    __shared__ int sdeg[RPB];
    int t = threadIdx.x;
    int blk = blockIdx.x;
    if (t < RPB) sdeg[t] = 0;
    __syncthreads();

    // edge scan: keep edges whose row belongs to this block
    for (int e = t; e < nnz_e; e += 256) {
        int r = row[e];
        if ((r >> 4) == blk) {
            int pos = atomicAdd(&sdeg[r & (RPB - 1)], 1);
            if (pos < KMAX) ell[r * KMAX + pos] = col[e];
        }
    }

    // X -> bf16 cast (grid-stride over float4s)
    int tid = blk * 256 + t;
    const int nthreads = PREP_BLOCKS * 256;
    for (int i = tid; i < ND / 4; i += nthreads) {
        float4 x = reinterpret_cast<const float4*>(X)[i];
        reinterpret_cast<ushort4*>(Xbf)[i] = f4_to_bf4(x);
    }

    // segment boundaries (independent of edges)
    for (int k = tid; k <= C; k += nthreads) start[k] = lower_bound(comm_ids, M, k);
    for (int k = tid; k <= N; k += nthreads) ostart[k] = lower_bound(comm_owner, C, k);

    __syncthreads();
    if (t < RPB) deg[blk * RPB + t] = sdeg[t];
}

// ---------------- K2: SpMM pass 1: bf16 X -> bf16 y1 ----------------
__global__ __launch_bounds__(256) void k_spmm1(const int* __restrict__ deg,
                                               const int* __restrict__ ell,
                                               const unsigned short* __restrict__ Xbf,
                                               unsigned short* __restrict__ Ybf) {
    int r = blockIdx.x * 4 + (threadIdx.x >> 6);
    int lane = threadIdx.x & 63;
    int dcnt = deg[r];
    int cnt = dcnt > KMAX ? KMAX : dcnt;
    float dr = rsqrtf((float)dcnt + 1.0f);

    const float4 xs = bf4_to_f4(*reinterpret_cast<const ushort4*>(&Xbf[(size_t)r * D + lane * 4]));
    float w0 = dr * dr;              // implicit self loop
    float4 acc0, acc1;
    acc0.x = w0 * xs.x; acc0.y = w0 * xs.y; acc0.z = w0 * xs.z; acc0.w = w0 * xs.w;
    acc1.x = 0.f; acc1.y = 0.f; acc1.z = 0.f; acc1.w = 0.f;

    int   c_l = 0;
    float w_l = 0.0f;
    if (lane < cnt) {
        c_l = ell[r * KMAX + lane];
        w_l = dr * rsqrtf((float)deg[c_l] + 1.0f);
    }
    int k = 0;
    for (; k + 1 < cnt; k += 2) {
        int   c0 = __shfl(c_l, k),  c1 = __shfl(c_l, k + 1);
        float u0 = __shfl(w_l, k),  u1 = __shfl(w_l, k + 1);
        const float4 x0 = bf4_to_f4(*reinterpret_cast<const ushort4*>(&Xbf[(size_t)c0 * D + lane * 4]));
        const float4 x1 = bf4_to_f4(*reinterpret_cast<const ushort4*>(&Xbf[(size_t)c1 * D + lane * 4]));
        acc0.x += u0 * x0.x; acc0.y += u0 * x0.y; acc0.z += u0 * x0.z; acc0.w += u0 * x0.w;
        acc1.x += u1 * x1.x; acc1.y += u1 * x1.y; acc1.z += u1 * x1.z; acc1.w += u1 * x1.w;
    }
    if (k < cnt) {
        int   c0 = __shfl(c_l, k);
        float u0 = __shfl(w_l, k);
        const float4 x0 = bf4_to_f4(*reinterpret_cast<const ushort4*>(&Xbf[(size_t)c0 * D + lane * 4]));
        acc0.x += u0 * x0.x; acc0.y += u0 * x0.y; acc0.z += u0 * x0.z; acc0.w += u0 * x0.w;
    }
    acc0.x += acc1.x; acc0.y += acc1.y; acc0.z += acc1.z; acc0.w += acc1.w;
    *reinterpret_cast<ushort4*>(&Ybf[(size_t)r * D + lane * 4]) = f4_to_bf4(acc0);
}

// ---------------- K3: SpMM pass 2: bf16 y1 -> bf16 prop + f32 relu first-half out ----------------
__global__ __launch_bounds__(256) void k_spmm2(const int* __restrict__ deg,
                                               const int* __restrict__ ell,
                                               const unsigned short* __restrict__ Ybf,
                                               unsigned short* __restrict__ Pbf,
                                               float* __restrict__ OUT) {
    int r = blockIdx.x * 4 + (threadIdx.x >> 6);
    int lane = threadIdx.x & 63;
    int dcnt = deg[r];
    int cnt = dcnt > KMAX ? KMAX : dcnt;
    float dr = rsqrtf((float)dcnt + 1.0f);

    const float4 xs = bf4_to_f4(*reinterpret_cast<const ushort4*>(&Ybf[(size_t)r * D + lane * 4]));
    float w0 = dr * dr;              // implicit self loop
    float4 acc0, acc1;
    acc0.x = w0 * xs.x; acc0.y = w0 * xs.y; acc0.z = w0 * xs.z; acc0.w = w0 * xs.w;
    acc1.x = 0.f; acc1.y = 0.f; acc1.z = 0.f; acc1.w = 0.f;

    int   c_l = 0;
    float w_l = 0.0f;
    if (lane < cnt) {
        c_l = ell[r * KMAX + lane];
        w_l = dr * rsqrtf((float)deg[c_l] + 1.0f);
    }
    int k = 0;
    for (; k + 1 < cnt; k += 2) {
        int   c0 = __shfl(c_l, k),  c1 = __shfl(c_l, k + 1);
        float u0 = __shfl(w_l, k),  u1 = __shfl(w_l, k + 1);
        const float4 x0 = bf4_to_f4(*reinterpret_cast<const ushort4*>(&Ybf[(size_t)c0 * D + lane * 4]));
        const float4 x1 = bf4_to_f4(*reinterpret_cast<const ushort4*>(&Ybf[(size_t)c1 * D + lane * 4]));
        acc0.x += u0 * x0.x; acc0.y += u0 * x0.y; acc0.z += u0 * x0.z; acc0.w += u0 * x0.w;
        acc1.x += u1 * x1.x; acc1.y += u1 * x1.y; acc1.z += u1 * x1.z; acc1.w += u1 * x1.w;
    }
    if (k < cnt) {
        int   c0 = __shfl(c_l, k);
        float u0 = __shfl(w_l, k);
        const float4 x0 = bf4_to_f4(*reinterpret_cast<const ushort4*>(&Ybf[(size_t)c0 * D + lane * 4]));
        acc0.x += u0 * x0.x; acc0.y += u0 * x0.y; acc0.z += u0 * x0.z; acc0.w += u0 * x0.w;
    }
    acc0.x += acc1.x; acc0.y += acc1.y; acc0.z += acc1.z; acc0.w += acc1.w;

    *reinterpret_cast<ushort4*>(&Pbf[(size_t)r * D + lane * 4]) = f4_to_bf4(acc0);
    float4 f;
    f.x = fmaxf(acc0.x, 0.f); f.y = fmaxf(acc0.y, 0.f);
    f.z = fmaxf(acc0.z, 0.f); f.w = fmaxf(acc0.w, 0.f);
    *reinterpret_cast<float4*>(&OUT[(size_t)r * (2 * D) + lane * 4]) = f;
}

// ---------------- K4: community mean (single comm per owner) -> out second half ----------------
// One node per 256-thread block; 4 waves split the member list 4-way interleaved; bf16 gathers.
__global__ __launch_bounds__(256) void k_owner(const int* __restrict__ member_nodes,
                                               const int* __restrict__ start,
                                               const int* __restrict__ ostart,
                                               const unsigned short* __restrict__ Pbf,
                                               float* __restrict__ out) {
    __shared__ float4 part[4][64];
    int wave = threadIdx.x >> 6;         // 0..3 : which quarter of the member list
    int lane = threadIdx.x & 63;
    int v = blockIdx.x;
    int cs = ostart[v], ce = ostart[v + 1];
    int single = (ce - cs == 1);

    float4 a0 = make_float4(0.f, 0.f, 0.f, 0.f);
    float4 a1 = a0, a2 = a0, a3 = a0;
    int cnt = 0;
    if (single) {
        int ms = start[cs], me = start[cs + 1];
        cnt = me - ms;
        int nh = cnt > wave ? ((cnt - wave + 3) >> 2) : 0;   // members at ms+wave+4*j
        for (int base = 0; base < nh; base += 64) {
            int j = base + lane;
            int id_l = 0;
            if (j < nh) id_l = member_nodes[ms + wave + 4 * j];
            int kmax = nh - base; if (kmax > 64) kmax = 64;
            int k = 0;
            for (; k + 3 < kmax; k += 4) {
                int n0 = __shfl(id_l, k),     n1 = __shfl(id_l, k + 1);
                int n2 = __shfl(id_l, k + 2), n3 = __shfl(id_l, k + 3);
                const float4 x0 = bf4_to_f4(*reinterpret_cast<const ushort4*>(&Pbf[(size_t)n0 * D + lane * 4]));
                const float4 x1 = bf4_to_f4(*reinterpret_cast<const ushort4*>(&Pbf[(size_t)n1 * D + lane * 4]));
                const float4 x2 = bf4_to_f4(*reinterpret_cast<const ushort4*>(&Pbf[(size_t)n2 * D + lane * 4]));
                const float4 x3 = bf4_to_f4(*reinterpret_cast<const ushort4*>(&Pbf[(size_t)n3 * D + lane * 4]));
                a0.x += x0.x; a0.y += x0.y; a0.z += x0.z; a0.w += x0.w;
                a1.x += x1.x; a1.y += x1.y; a1.z += x1.z; a1.w += x1.w;
                a2.x += x2.x; a2.y += x2.y; a2.z += x2.z; a2.w += x2.w;
                a3.x += x3.x; a3.y += x3.y; a3.z += x3.z; a3.w += x3.w;
            }
            for (; k < kmax; ++k) {
                int n0 = __shfl(id_l, k);
                const float4 x0 = bf4_to_f4(*reinterpret_cast<const ushort4*>(&Pbf[(size_t)n0 * D + lane * 4]));
                a0.x += x0.x; a0.y += x0.y; a0.z += x0.z; a0.w += x0.w;
            }
        }
        a0.x += a1.x + a2.x + a3.x;
        a0.y += a1.y + a2.y + a3.y;
        a0.z += a1.z + a2.z + a3.z;
        a0.w += a1.w + a2.w + a3.w;
    }
    part[wave][lane] = a0;
    __syncthreads();                      // uniform barrier

    if (wave == 0) {
        float4 second;
        if (single) {
            float4 p1 = part[1][lane], p2 = part[2][lane], p3 = part[3][lane];
            float inv = 1.0f / (float)cnt;
            second.x = (a0.x + p1.x + p2.x + p3.x) * inv;
            second.y = (a0.y + p1.y + p2.y + p3.y) * inv;
            second.z = (a0.z + p1.z + p2.z + p3.z) * inv;
            second.w = (a0.w + p1.w + p2.w + p3.w) * inv;
        } else if (cs == ce) {
            second = bf4_to_f4(*reinterpret_cast<const ushort4*>(&Pbf[(size_t)v * D + lane * 4]));
        } else {
            // general multi-community path (dead on this data, kept for safety)
            float4 mx = make_float4(-INFINITY, -INFINITY, -INFINITY, -INFINITY);
            for (int c = cs; c < ce; ++c) {
                int ms = start[c], me = start[c + 1];
                float4 sum = make_float4(0.f, 0.f, 0.f, 0.f);
                for (int m = ms; m < me; ++m) {
                    int n0 = member_nodes[m];
                    const float4 x0 = bf4_to_f4(*reinterpret_cast<const ushort4*>(&Pbf[(size_t)n0 * D + lane * 4]));
                    sum.x += x0.x; sum.y += x0.y; sum.z += x0.z; sum.w += x0.w;
                }
                float inv = 1.0f / (float)(me - ms);
                mx.x = fmaxf(mx.x, sum.x * inv); mx.y = fmaxf(mx.y, sum.y * inv);
                mx.z = fmaxf(mx.z, sum.z * inv); mx.w = fmaxf(mx.w, sum.w * inv);
            }
            second = mx;
        }
        second.x = fmaxf(second.x, 0.f); second.y = fmaxf(second.y, 0.f);
        second.z = fmaxf(second.z, 0.f); second.w = fmaxf(second.w, 0.f);
        *reinterpret_cast<float4*>(&out[(size_t)v * (2 * D) + D + lane * 4]) = second;
    }
}

extern "C" void kernel_launch(void* const* d_in, const int* in_sizes, int n_in,
                              void* d_out, int out_size, void* d_ws, size_t ws_size,
                              hipStream_t stream) {
    const int*   edge_index   = (const int*)d_in[0];
    const float* X            = (const float*)d_in[1];
    const int*   member_nodes = (const int*)d_in[2];
    const int*   comm_ids     = (const int*)d_in[3];
    const int*   comm_owner   = (const int*)d_in[4];

    const int nnz_e = in_sizes[0] / 2;
    const int M     = in_sizes[2];
    const int C     = in_sizes[4];

    int* ws = (int*)d_ws;
    int off = 0;
    int*   deg    = ws + off; off += N;
    int*   ell    = ws + off; off += N * KMAX;
    off = (off + 3) & ~3;                        // 16B align
    unsigned short* xbf = (unsigned short*)(ws + off); off += ND / 2;  // bf16 X (2 MB)
    unsigned short* y1bf = (unsigned short*)(ws + off); off += ND / 2; // bf16 y1 (2 MB)
    unsigned short* pbf = (unsigned short*)(ws + off); off += ND / 2;  // bf16 prop (2 MB)
    int*   start  = ws + off; off += C + 1;
    int*   ostart = ws + off; off += N + 1;

    const int* row = edge_index;
    const int* col = edge_index + nnz_e;
    float* outp = (float*)d_out;

    k_prep<<<PREP_BLOCKS, 256, 0, stream>>>(row, col, nnz_e, X, xbf, deg, ell,
                                            comm_ids, M, C, start, comm_owner, ostart);
    k_spmm1<<<ROW_BLOCKS, 256, 0, stream>>>(deg, ell, xbf, y1bf);
    k_spmm2<<<ROW_BLOCKS, 256, 0, stream>>>(deg, ell, y1bf, pbf, outp);
    k_owner<<<N, 256, 0, stream>>>(member_nodes, start, ostart, pbf, outp);
}

// Round 11
// 46.923 us; speedup vs baseline: 1.3479x; 1.3479x over previous
//
#include <hip/hip_runtime.h>
#include <math.h>

constexpr int N = 4096;
constexpr int D = 256;
constexpr int ND = N * D;
constexpr int KMAX = 32;              // safe bound on directed degree (Poisson(~6))
constexpr int ROW_BLOCKS = N / 4;     // 4 waves (rows) per 256-thread block
constexpr int RPB = 32;               // rows per prep block
constexpr int PREP_BLOCKS = N / RPB;  // 128
constexpr int PREP_T = 1024;

// ---- bf16 helpers (RNE) ----
__device__ inline unsigned short f2bf(float f) {
    unsigned u = __float_as_uint(f);
    unsigned r = (u + 0x7FFFu + ((u >> 16) & 1u)) >> 16;
    return (unsigned short)r;
}
__device__ inline float bf2f(unsigned short h) {
    return __uint_as_float(((unsigned)h) << 16);
}
__device__ inline float4 bf4_to_f4(ushort4 s) {
    return make_float4(bf2f(s.x), bf2f(s.y), bf2f(s.z), bf2f(s.w));
}
__device__ inline ushort4 f4_to_bf4(float4 f) {
    ushort4 s; s.x = f2bf(f.x); s.y = f2bf(f.y); s.z = f2bf(f.z); s.w = f2bf(f.w);
    return s;
}

__device__ inline int lower_bound(const int* __restrict__ a, int n, int key) {
    int lo = 0, hi = n;
    while (lo < hi) {
        int mid = (lo + hi) >> 1;
        if (a[mid] < key) lo = mid + 1; else hi = mid;
    }
    return lo;
}

// ---------------- K1: fused prep (FAST version) ----------------
// Block b owns rows [32b, 32b+32). 1024 threads scan row[] via int4 (6 iters,
// independent -> pipelined); col[] loaded only on match (~192/block).
// Also: X->bf16 cast and segment-bound binary searches, grid-strided.
__global__ __launch_bounds__(PREP_T) void k_prep(const int* __restrict__ row,
                                                 const int* __restrict__ col, int nnz_e,
                                                 const float* __restrict__ X,
                                                 unsigned short* __restrict__ Xbf,
                                                 int* __restrict__ deg, int* __restrict__ ell,
                                                 const int* __restrict__ comm_ids, int M, int C,
                                                 int* __restrict__ start,
                                                 const int* __restrict__ comm_owner,
                                                 int* __restrict__ ostart) {
    __shared__ int sdeg[RPB];
    int t = threadIdx.x;
    int blk = blockIdx.x;
    if (t < RPB) sdeg[t] = 0;
    __syncthreads();

    // vectorized edge scan (row[] only; col on match)
    int nnz4 = nnz_e >> 2;
    for (int i = t; i < nnz4; i += PREP_T) {
        int4 r4 = reinterpret_cast<const int4*>(row)[i];
        int e = i << 2;
        if ((r4.x >> 5) == blk) {
            int pos = atomicAdd(&sdeg[r4.x & (RPB - 1)], 1);
            if (pos < KMAX) ell[r4.x * KMAX + pos] = col[e];
        }
        if ((r4.y >> 5) == blk) {
            int pos = atomicAdd(&sdeg[r4.y & (RPB - 1)], 1);
            if (pos < KMAX) ell[r4.y * KMAX + pos] = col[e + 1];
        }
        if ((r4.z >> 5) == blk) {
            int pos = atomicAdd(&sdeg[r4.z & (RPB - 1)], 1);
            if (pos < KMAX) ell[r4.z * KMAX + pos] = col[e + 2];
        }
        if ((r4.w >> 5) == blk) {
            int pos = atomicAdd(&sdeg[r4.w & (RPB - 1)], 1);
            if (pos < KMAX) ell[r4.w * KMAX + pos] = col[e + 3];
        }
    }
    for (int e = (nnz4 << 2) + t; e < nnz_e; e += PREP_T) {   // tail (none if nnz%4==0)
        int r = row[e];
        if ((r >> 5) == blk) {
            int pos = atomicAdd(&sdeg[r & (RPB - 1)], 1);
            if (pos < KMAX) ell[r * KMAX + pos] = col[e];
        }
    }

    // X -> bf16 cast (grid-stride over float4s: 2 per thread)
    int tid = blk * PREP_T + t;
    const int nthreads = PREP_BLOCKS * PREP_T;
    for (int i = tid; i < ND / 4; i += nthreads) {
        float4 x = reinterpret_cast<const float4*>(X)[i];
        reinterpret_cast<ushort4*>(Xbf)[i] = f4_to_bf4(x);
    }

    // segment boundaries (independent of edges)
    for (int k = tid; k <= C; k += nthreads) start[k] = lower_bound(comm_ids, M, k);
    for (int k = tid; k <= N; k += nthreads) ostart[k] = lower_bound(comm_owner, C, k);

    __syncthreads();
    if (t < RPB) deg[blk * RPB + t] = sdeg[t];
}

// ---------------- K2: SpMM pass 1: bf16 X -> bf16 y1 ----------------
__global__ __launch_bounds__(256) void k_spmm1(const int* __restrict__ deg,
                                               const int* __restrict__ ell,
                                               const unsigned short* __restrict__ Xbf,
                                               unsigned short* __restrict__ Ybf) {
    int r = blockIdx.x * 4 + (threadIdx.x >> 6);
    int lane = threadIdx.x & 63;
    int dcnt = deg[r];
    int cnt = dcnt > KMAX ? KMAX : dcnt;
    float dr = rsqrtf((float)dcnt + 1.0f);

    const float4 xs = bf4_to_f4(*reinterpret_cast<const ushort4*>(&Xbf[(size_t)r * D + lane * 4]));
    float w0 = dr * dr;              // implicit self loop
    float4 acc0, acc1;
    acc0.x = w0 * xs.x; acc0.y = w0 * xs.y; acc0.z = w0 * xs.z; acc0.w = w0 * xs.w;
    acc1.x = 0.f; acc1.y = 0.f; acc1.z = 0.f; acc1.w = 0.f;

    int   c_l = 0;
    float w_l = 0.0f;
    if (lane < cnt) {
        c_l = ell[r * KMAX + lane];
        w_l = dr * rsqrtf((float)deg[c_l] + 1.0f);
    }
    int k = 0;
    for (; k + 1 < cnt; k += 2) {
        int   c0 = __shfl(c_l, k),  c1 = __shfl(c_l, k + 1);
        float u0 = __shfl(w_l, k),  u1 = __shfl(w_l, k + 1);
        const float4 x0 = bf4_to_f4(*reinterpret_cast<const ushort4*>(&Xbf[(size_t)c0 * D + lane * 4]));
        const float4 x1 = bf4_to_f4(*reinterpret_cast<const ushort4*>(&Xbf[(size_t)c1 * D + lane * 4]));
        acc0.x += u0 * x0.x; acc0.y += u0 * x0.y; acc0.z += u0 * x0.z; acc0.w += u0 * x0.w;
        acc1.x += u1 * x1.x; acc1.y += u1 * x1.y; acc1.z += u1 * x1.z; acc1.w += u1 * x1.w;
    }
    if (k < cnt) {
        int   c0 = __shfl(c_l, k);
        float u0 = __shfl(w_l, k);
        const float4 x0 = bf4_to_f4(*reinterpret_cast<const ushort4*>(&Xbf[(size_t)c0 * D + lane * 4]));
        acc0.x += u0 * x0.x; acc0.y += u0 * x0.y; acc0.z += u0 * x0.z; acc0.w += u0 * x0.w;
    }
    acc0.x += acc1.x; acc0.y += acc1.y; acc0.z += acc1.z; acc0.w += acc1.w;
    *reinterpret_cast<ushort4*>(&Ybf[(size_t)r * D + lane * 4]) = f4_to_bf4(acc0);
}

// ---------------- K3: SpMM pass 2: bf16 y1 -> bf16 prop + f32 relu first-half out ----------------
__global__ __launch_bounds__(256) void k_spmm2(const int* __restrict__ deg,
                                               const int* __restrict__ ell,
                                               const unsigned short* __restrict__ Ybf,
                                               unsigned short* __restrict__ Pbf,
                                               float* __restrict__ OUT) {
    int r = blockIdx.x * 4 + (threadIdx.x >> 6);
    int lane = threadIdx.x & 63;
    int dcnt = deg[r];
    int cnt = dcnt > KMAX ? KMAX : dcnt;
    float dr = rsqrtf((float)dcnt + 1.0f);

    const float4 xs = bf4_to_f4(*reinterpret_cast<const ushort4*>(&Ybf[(size_t)r * D + lane * 4]));
    float w0 = dr * dr;              // implicit self loop
    float4 acc0, acc1;
    acc0.x = w0 * xs.x; acc0.y = w0 * xs.y; acc0.z = w0 * xs.z; acc0.w = w0 * xs.w;
    acc1.x = 0.f; acc1.y = 0.f; acc1.z = 0.f; acc1.w = 0.f;

    int   c_l = 0;
    float w_l = 0.0f;
    if (lane < cnt) {
        c_l = ell[r * KMAX + lane];
        w_l = dr * rsqrtf((float)deg[c_l] + 1.0f);
    }
    int k = 0;
    for (; k + 1 < cnt; k += 2) {
        int   c0 = __shfl(c_l, k),  c1 = __shfl(c_l, k + 1);
        float u0 = __shfl(w_l, k),  u1 = __shfl(w_l, k + 1);
        const float4 x0 = bf4_to_f4(*reinterpret_cast<const ushort4*>(&Ybf[(size_t)c0 * D + lane * 4]));
        const float4 x1 = bf4_to_f4(*reinterpret_cast<const ushort4*>(&Ybf[(size_t)c1 * D + lane * 4]));
        acc0.x += u0 * x0.x; acc0.y += u0 * x0.y; acc0.z += u0 * x0.z; acc0.w += u0 * x0.w;
        acc1.x += u1 * x1.x; acc1.y += u1 * x1.y; acc1.z += u1 * x1.z; acc1.w += u1 * x1.w;
    }
    if (k < cnt) {
        int   c0 = __shfl(c_l, k);
        float u0 = __shfl(w_l, k);
        const float4 x0 = bf4_to_f4(*reinterpret_cast<const ushort4*>(&Ybf[(size_t)c0 * D + lane * 4]));
        acc0.x += u0 * x0.x; acc0.y += u0 * x0.y; acc0.z += u0 * x0.z; acc0.w += u0 * x0.w;
    }
    acc0.x += acc1.x; acc0.y += acc1.y; acc0.z += acc1.z; acc0.w += acc1.w;

    *reinterpret_cast<ushort4*>(&Pbf[(size_t)r * D + lane * 4]) = f4_to_bf4(acc0);
    float4 f;
    f.x = fmaxf(acc0.x, 0.f); f.y = fmaxf(acc0.y, 0.f);
    f.z = fmaxf(acc0.z, 0.f); f.w = fmaxf(acc0.w, 0.f);
    *reinterpret_cast<float4*>(&OUT[(size_t)r * (2 * D) + lane * 4]) = f;
}

// ---------------- K4: community mean (single comm per owner) -> out second half ----------------
__global__ __launch_bounds__(256) void k_owner(const int* __restrict__ member_nodes,
                                               const int* __restrict__ start,
                                               const int* __restrict__ ostart,
                                               const unsigned short* __restrict__ Pbf,
                                               float* __restrict__ out) {
    __shared__ float4 part[4][64];
    int wave = threadIdx.x >> 6;         // 0..3 : which quarter of the member list
    int lane = threadIdx.x & 63;
    int v = blockIdx.x;
    int cs = ostart[v], ce = ostart[v + 1];
    int single = (ce - cs == 1);

    float4 a0 = make_float4(0.f, 0.f, 0.f, 0.f);
    float4 a1 = a0, a2 = a0, a3 = a0;
    int cnt = 0;
    if (single) {
        int ms = start[cs], me = start[cs + 1];
        cnt = me - ms;
        int nh = cnt > wave ? ((cnt - wave + 3) >> 2) : 0;   // members at ms+wave+4*j
        for (int base = 0; base < nh; base += 64) {
            int j = base + lane;
            int id_l = 0;
            if (j < nh) id_l = member_nodes[ms + wave + 4 * j];
            int kmax = nh - base; if (kmax > 64) kmax = 64;
            int k = 0;
            for (; k + 3 < kmax; k += 4) {
                int n0 = __shfl(id_l, k),     n1 = __shfl(id_l, k + 1);
                int n2 = __shfl(id_l, k + 2), n3 = __shfl(id_l, k + 3);
                const float4 x0 = bf4_to_f4(*reinterpret_cast<const ushort4*>(&Pbf[(size_t)n0 * D + lane * 4]));
                const float4 x1 = bf4_to_f4(*reinterpret_cast<const ushort4*>(&Pbf[(size_t)n1 * D + lane * 4]));
                const float4 x2 = bf4_to_f4(*reinterpret_cast<const ushort4*>(&Pbf[(size_t)n2 * D + lane * 4]));
                const float4 x3 = bf4_to_f4(*reinterpret_cast<const ushort4*>(&Pbf[(size_t)n3 * D + lane * 4]));
                a0.x += x0.x; a0.y += x0.y; a0.z += x0.z; a0.w += x0.w;
                a1.x += x1.x; a1.y += x1.y; a1.z += x1.z; a1.w += x1.w;
                a2.x += x2.x; a2.y += x2.y; a2.z += x2.z; a2.w += x2.w;
                a3.x += x3.x; a3.y += x3.y; a3.z += x3.z; a3.w += x3.w;
            }
            for (; k < kmax; ++k) {
                int n0 = __shfl(id_l, k);
                const float4 x0 = bf4_to_f4(*reinterpret_cast<const ushort4*>(&Pbf[(size_t)n0 * D + lane * 4]));
                a0.x += x0.x; a0.y += x0.y; a0.z += x0.z; a0.w += x0.w;
            }
        }
        a0.x += a1.x + a2.x + a3.x;
        a0.y += a1.y + a2.y + a3.y;
        a0.z += a1.z + a2.z + a3.z;
        a0.w += a1.w + a2.w + a3.w;
    }
    part[wave][lane] = a0;
    __syncthreads();                      // uniform barrier

    if (wave == 0) {
        float4 second;
        if (single) {
            float4 p1 = part[1][lane], p2 = part[2][lane], p3 = part[3][lane];
            float inv = 1.0f / (float)cnt;
            second.x = (a0.x + p1.x + p2.x + p3.x) * inv;
            second.y = (a0.y + p1.y + p2.y + p3.y) * inv;
            second.z = (a0.z + p1.z + p2.z + p3.z) * inv;
            second.w = (a0.w + p1.w + p2.w + p3.w) * inv;
        } else if (cs == ce) {
            second = bf4_to_f4(*reinterpret_cast<const ushort4*>(&Pbf[(size_t)v * D + lane * 4]));
        } else {
            // general multi-community path (dead on this data, kept for safety)
            float4 mx = make_float4(-INFINITY, -INFINITY, -INFINITY, -INFINITY);
            for (int c = cs; c < ce; ++c) {
                int ms = start[c], me = start[c + 1];
                float4 sum = make_float4(0.f, 0.f, 0.f, 0.f);
                for (int m = ms; m < me; ++m) {
                    int n0 = member_nodes[m];
                    const float4 x0 = bf4_to_f4(*reinterpret_cast<const ushort4*>(&Pbf[(size_t)n0 * D + lane * 4]));
                    sum.x += x0.x; sum.y += x0.y; sum.z += x0.z; sum.w += x0.w;
                }
                float inv = 1.0f / (float)(me - ms);
                mx.x = fmaxf(mx.x, sum.x * inv); mx.y = fmaxf(mx.y, sum.y * inv);
                mx.z = fmaxf(mx.z, sum.z * inv); mx.w = fmaxf(mx.w, sum.w * inv);
            }
            second = mx;
        }
        second.x = fmaxf(second.x, 0.f); second.y = fmaxf(second.y, 0.f);
        second.z = fmaxf(second.z, 0.f); second.w = fmaxf(second.w, 0.f);
        *reinterpret_cast<float4*>(&out[(size_t)v * (2 * D) + D + lane * 4]) = second;
    }
}

extern "C" void kernel_launch(void* const* d_in, const int* in_sizes, int n_in,
                              void* d_out, int out_size, void* d_ws, size_t ws_size,
                              hipStream_t stream) {
    const int*   edge_index   = (const int*)d_in[0];
    const float* X            = (const float*)d_in[1];
    const int*   member_nodes = (const int*)d_in[2];
    const int*   comm_ids     = (const int*)d_in[3];
    const int*   comm_owner   = (const int*)d_in[4];

    const int nnz_e = in_sizes[0] / 2;
    const int M     = in_sizes[2];
    const int C     = in_sizes[4];

    int* ws = (int*)d_ws;
    int off = 0;
    int*   deg    = ws + off; off += N;
    int*   ell    = ws + off; off += N * KMAX;
    off = (off + 3) & ~3;                        // 16B align
    unsigned short* xbf = (unsigned short*)(ws + off); off += ND / 2;  // bf16 X (2 MB)
    unsigned short* y1bf = (unsigned short*)(ws + off); off += ND / 2; // bf16 y1 (2 MB)
    unsigned short* pbf = (unsigned short*)(ws + off); off += ND / 2;  // bf16 prop (2 MB)
    int*   start  = ws + off; off += C + 1;
    int*   ostart = ws + off; off += N + 1;

    const int* row = edge_index;
    const int* col = edge_index + nnz_e;
    float* outp = (float*)d_out;

    k_prep<<<PREP_BLOCKS, PREP_T, 0, stream>>>(row, col, nnz_e, X, xbf, deg, ell,
                                               comm_ids, M, C, start, comm_owner, ostart);
    k_spmm1<<<ROW_BLOCKS, 256, 0, stream>>>(deg, ell, xbf, y1bf);
    k_spmm2<<<ROW_BLOCKS, 256, 0, stream>>>(deg, ell, y1bf, pbf, outp);
    k_owner<<<N, 256, 0, stream>>>(member_nodes, start, ostart, pbf, outp);
}

// Round 13
// 45.073 us; speedup vs baseline: 1.4032x; 1.0410x over previous
//
#include <hip/hip_runtime.h>
#include <math.h>

constexpr int N = 4096;
constexpr int D = 256;
constexpr int ND = N * D;
constexpr int KMAX = 32;             // safe bound on directed degree (Poisson(~6))
constexpr int ROW_BLOCKS = N / 4;    // 4 waves (rows) per 256-thread block

// ---- bf16 helpers (RNE) ----
__device__ inline unsigned short f2bf(float f) {
    unsigned u = __float_as_uint(f);
    unsigned r = (u + 0x7FFFu + ((u >> 16) & 1u)) >> 16;
    return (unsigned short)r;
}
__device__ inline float bf2f(unsigned short h) {
    return __uint_as_float(((unsigned)h) << 16);
}
__device__ inline float4 bf4_to_f4(ushort4 s) {
    return make_float4(bf2f(s.x), bf2f(s.y), bf2f(s.z), bf2f(s.w));
}
__device__ inline ushort4 f4_to_bf4(float4 f) {
    ushort4 s; s.x = f2bf(f.x); s.y = f2bf(f.y); s.z = f2bf(f.z); s.w = f2bf(f.w);
    return s;
}

__device__ inline int lower_bound(const int* __restrict__ a, int n, int key) {
    int lo = 0, hi = n;
    while (lo < hi) {
        int mid = (lo + hi) >> 1;
        if (a[mid] < key) lo = mid + 1; else hi = mid;
    }
    return lo;
}

// 64-lane ascending bitonic sort (int keys). Lanes hold one key each.
__device__ inline int wave_sort_asc(int v, int lane) {
    for (int k = 2; k <= 64; k <<= 1) {
        for (int j = k >> 1; j >= 1; j >>= 1) {
            int other = __shfl_xor(v, j);
            bool up = ((lane & k) == 0);          // ascending region of this merge
            bool hi = ((lane & j) != 0);          // upper partner of the pair
            bool keepMax = (hi == up);
            int mn = v < other ? v : other;
            int mx = v > other ? v : other;
            v = keepMax ? mx : mn;
        }
    }
    return v;
}

// ---------------- K1: zero deg + cast X -> bf16 ----------------
__global__ __launch_bounds__(256) void k_pre(int* __restrict__ deg,
                                             const float* __restrict__ X,
                                             unsigned short* __restrict__ Xbf) {
    int tid = blockIdx.x * blockDim.x + threadIdx.x;
    if (tid < N) deg[tid] = 0;
    int stride = gridDim.x * blockDim.x;
    for (int i = tid; i < ND / 4; i += stride) {
        float4 x = reinterpret_cast<const float4*>(X)[i];
        reinterpret_cast<ushort4*>(Xbf)[i] = f4_to_bf4(x);
    }
}

// ---------------- K2: ELL build (atomic slot scatter) + segment bounds ----------------
// Slot ORDER is nondeterministic here; k_spmm1 canonicalizes by sorting each row.
__global__ void k_build(const int* __restrict__ row, const int* __restrict__ col,
                        int nnz_e, int* __restrict__ deg, int* __restrict__ ell,
                        const int* __restrict__ comm_ids, int M, int C,
                        int* __restrict__ start,
                        const int* __restrict__ comm_owner, int* __restrict__ ostart) {
    int t = blockIdx.x * blockDim.x + threadIdx.x;
    if (t < nnz_e) {
        int r = row[t], c = col[t];
        int pos = atomicAdd(&deg[r], 1);
        if (pos < KMAX) ell[r * KMAX + pos] = c;
    }
    if (t <= C) start[t] = lower_bound(comm_ids, M, t);
    if (t <= N) ostart[t] = lower_bound(comm_owner, C, t);
}

// ---------------- K3: SpMM pass 1 (bf16 X -> bf16 y1), canonicalizing ELL ----------------
// Sorts the row's neighbor list across lanes (deterministic multiset order),
// writes it back so every later consumer sees a bit-deterministic ELL.
__global__ __launch_bounds__(256) void k_spmm1(const int* __restrict__ deg,
                                               int* __restrict__ ell,
                                               const unsigned short* __restrict__ Xbf,
                                               unsigned short* __restrict__ Ybf) {
    int r = blockIdx.x * 4 + (threadIdx.x >> 6);
    int lane = threadIdx.x & 63;
    int dcnt = deg[r];
    int cnt = dcnt > KMAX ? KMAX : dcnt;
    float dr = rsqrtf((float)dcnt + 1.0f);

    // load + canonical sort + writeback
    int c_raw = (lane < cnt) ? ell[r * KMAX + lane] : 0x7FFFFFFF;
    int c_s = wave_sort_asc(c_raw, lane);
    if (lane < cnt) ell[r * KMAX + lane] = c_s;

    const float4 xs = bf4_to_f4(*reinterpret_cast<const ushort4*>(&Xbf[(size_t)r * D + lane * 4]));
    float w0 = dr * dr;              // implicit self loop
    float4 acc0, acc1;
    acc0.x = w0 * xs.x; acc0.y = w0 * xs.y; acc0.z = w0 * xs.z; acc0.w = w0 * xs.w;
    acc1.x = 0.f; acc1.y = 0.f; acc1.z = 0.f; acc1.w = 0.f;

    int   c_l = 0;
    float w_l = 0.0f;
    if (lane < cnt) {
        c_l = c_s;
        w_l = dr * rsqrtf((float)deg[c_l] + 1.0f);
    }
    int k = 0;
    for (; k + 1 < cnt; k += 2) {
        int   c0 = __shfl(c_l, k),  c1 = __shfl(c_l, k + 1);
        float u0 = __shfl(w_l, k),  u1 = __shfl(w_l, k + 1);
        const float4 x0 = bf4_to_f4(*reinterpret_cast<const ushort4*>(&Xbf[(size_t)c0 * D + lane * 4]));
        const float4 x1 = bf4_to_f4(*reinterpret_cast<const ushort4*>(&Xbf[(size_t)c1 * D + lane * 4]));
        acc0.x += u0 * x0.x; acc0.y += u0 * x0.y; acc0.z += u0 * x0.z; acc0.w += u0 * x0.w;
        acc1.x += u1 * x1.x; acc1.y += u1 * x1.y; acc1.z += u1 * x1.z; acc1.w += u1 * x1.w;
    }
    if (k < cnt) {
        int   c0 = __shfl(c_l, k);
        float u0 = __shfl(w_l, k);
        const float4 x0 = bf4_to_f4(*reinterpret_cast<const ushort4*>(&Xbf[(size_t)c0 * D + lane * 4]));
        acc0.x += u0 * x0.x; acc0.y += u0 * x0.y; acc0.z += u0 * x0.z; acc0.w += u0 * x0.w;
    }
    acc0.x += acc1.x; acc0.y += acc1.y; acc0.z += acc1.z; acc0.w += acc1.w;
    *reinterpret_cast<ushort4*>(&Ybf[(size_t)r * D + lane * 4]) = f4_to_bf4(acc0);
}

// ---------------- K4: SpMM pass 2 (sorted ELL): bf16 y1 -> bf16 prop + relu first half ----------------
__global__ __launch_bounds__(256) void k_spmm2(const int* __restrict__ deg,
                                               const int* __restrict__ ell,
                                               const unsigned short* __restrict__ Ybf,
                                               unsigned short* __restrict__ Pbf,
                                               float* __restrict__ OUT) {
    int r = blockIdx.x * 4 + (threadIdx.x >> 6);
    int lane = threadIdx.x & 63;
    int dcnt = deg[r];
    int cnt = dcnt > KMAX ? KMAX : dcnt;
    float dr = rsqrtf((float)dcnt + 1.0f);

    const float4 xs = bf4_to_f4(*reinterpret_cast<const ushort4*>(&Ybf[(size_t)r * D + lane * 4]));
    float w0 = dr * dr;              // implicit self loop
    float4 acc0, acc1;
    acc0.x = w0 * xs.x; acc0.y = w0 * xs.y; acc0.z = w0 * xs.z; acc0.w = w0 * xs.w;
    acc1.x = 0.f; acc1.y = 0.f; acc1.z = 0.f; acc1.w = 0.f;

    int   c_l = 0;
    float w_l = 0.0f;
    if (lane < cnt) {
        c_l = ell[r * KMAX + lane];      // sorted by k_spmm1 -> deterministic order
        w_l = dr * rsqrtf((float)deg[c_l] + 1.0f);
    }
    int k = 0;
    for (; k + 1 < cnt; k += 2) {
        int   c0 = __shfl(c_l, k),  c1 = __shfl(c_l, k + 1);
        float u0 = __shfl(w_l, k),  u1 = __shfl(w_l, k + 1);
        const float4 x0 = bf4_to_f4(*reinterpret_cast<const ushort4*>(&Ybf[(size_t)c0 * D + lane * 4]));
        const float4 x1 = bf4_to_f4(*reinterpret_cast<const ushort4*>(&Ybf[(size_t)c1 * D + lane * 4]));
        acc0.x += u0 * x0.x; acc0.y += u0 * x0.y; acc0.z += u0 * x0.z; acc0.w += u0 * x0.w;
        acc1.x += u1 * x1.x; acc1.y += u1 * x1.y; acc1.z += u1 * x1.z; acc1.w += u1 * x1.w;
    }
    if (k < cnt) {
        int   c0 = __shfl(c_l, k);
        float u0 = __shfl(w_l, k);
        const float4 x0 = bf4_to_f4(*reinterpret_cast<const ushort4*>(&Ybf[(size_t)c0 * D + lane * 4]));
        acc0.x += u0 * x0.x; acc0.y += u0 * x0.y; acc0.z += u0 * x0.z; acc0.w += u0 * x0.w;
    }
    acc0.x += acc1.x; acc0.y += acc1.y; acc0.z += acc1.z; acc0.w += acc1.w;

    *reinterpret_cast<ushort4*>(&Pbf[(size_t)r * D + lane * 4]) = f4_to_bf4(acc0);
    float4 f;
    f.x = fmaxf(acc0.x, 0.f); f.y = fmaxf(acc0.y, 0.f);
    f.z = fmaxf(acc0.z, 0.f); f.w = fmaxf(acc0.w, 0.f);
    *reinterpret_cast<float4*>(&OUT[(size_t)r * (2 * D) + lane * 4]) = f;
}

// ---------------- K5: community mean (single comm per owner) -> out second half ----------------
__global__ __launch_bounds__(256) void k_owner(const int* __restrict__ member_nodes,
                                               const int* __restrict__ start,
                                               const int* __restrict__ ostart,
                                               const unsigned short* __restrict__ Pbf,
                                               float* __restrict__ out) {
    __shared__ float4 part[4][64];
    int wave = threadIdx.x >> 6;         // 0..3 : which quarter of the member list
    int lane = threadIdx.x & 63;
    int v = blockIdx.x;
    int cs = ostart[v], ce = ostart[v + 1];
    int single = (ce - cs == 1);

    float4 a0 = make_float4(0.f, 0.f, 0.f, 0.f);
    float4 a1 = a0, a2 = a0, a3 = a0;
    int cnt = 0;
    if (single) {
        int ms = start[cs], me = start[cs + 1];
        cnt = me - ms;
        int nh = cnt > wave ? ((cnt - wave + 3) >> 2) : 0;   // members at ms+wave+4*j
        for (int base = 0; base < nh; base += 64) {
            int j = base + lane;
            int id_l = 0;
            if (j < nh) id_l = member_nodes[ms + wave + 4 * j];
            int kmax = nh - base; if (kmax > 64) kmax = 64;
            int k = 0;
            for (; k + 3 < kmax; k += 4) {
                int n0 = __shfl(id_l, k),     n1 = __shfl(id_l, k + 1);
                int n2 = __shfl(id_l, k + 2), n3 = __shfl(id_l, k + 3);
                const float4 x0 = bf4_to_f4(*reinterpret_cast<const ushort4*>(&Pbf[(size_t)n0 * D + lane * 4]));
                const float4 x1 = bf4_to_f4(*reinterpret_cast<const ushort4*>(&Pbf[(size_t)n1 * D + lane * 4]));
                const float4 x2 = bf4_to_f4(*reinterpret_cast<const ushort4*>(&Pbf[(size_t)n2 * D + lane * 4]));
                const float4 x3 = bf4_to_f4(*reinterpret_cast<const ushort4*>(&Pbf[(size_t)n3 * D + lane * 4]));
                a0.x += x0.x; a0.y += x0.y; a0.z += x0.z; a0.w += x0.w;
                a1.x += x1.x; a1.y += x1.y; a1.z += x1.z; a1.w += x1.w;
                a2.x += x2.x; a2.y += x2.y; a2.z += x2.z; a2.w += x2.w;
                a3.x += x3.x; a3.y += x3.y; a3.z += x3.z; a3.w += x3.w;
            }
            for (; k < kmax; ++k) {
                int n0 = __shfl(id_l, k);
                const float4 x0 = bf4_to_f4(*reinterpret_cast<const ushort4*>(&Pbf[(size_t)n0 * D + lane * 4]));
                a0.x += x0.x; a0.y += x0.y; a0.z += x0.z; a0.w += x0.w;
            }
        }
        a0.x += a1.x + a2.x + a3.x;
        a0.y += a1.y + a2.y + a3.y;
        a0.z += a1.z + a2.z + a3.z;
        a0.w += a1.w + a2.w + a3.w;
    }
    part[wave][lane] = a0;
    __syncthreads();                      // uniform barrier

    if (wave == 0) {
        float4 second;
        if (single) {
            float4 p1 = part[1][lane], p2 = part[2][lane], p3 = part[3][lane];
            float inv = 1.0f / (float)cnt;
            second.x = (a0.x + p1.x + p2.x + p3.x) * inv;
            second.y = (a0.y + p1.y + p2.y + p3.y) * inv;
            second.z = (a0.z + p1.z + p2.z + p3.z) * inv;
            second.w = (a0.w + p1.w + p2.w + p3.w) * inv;
        } else if (cs == ce) {
            second = bf4_to_f4(*reinterpret_cast<const ushort4*>(&Pbf[(size_t)v * D + lane * 4]));
        } else {
            // general multi-community path (dead on this data, kept for safety)
            float4 mx = make_float4(-INFINITY, -INFINITY, -INFINITY, -INFINITY);
            for (int c = cs; c < ce; ++c) {
                int ms = start[c], me = start[c + 1];
                float4 sum = make_float4(0.f, 0.f, 0.f, 0.f);
                for (int m = ms; m < me; ++m) {
                    int n0 = member_nodes[m];
                    const float4 x0 = bf4_to_f4(*reinterpret_cast<const ushort4*>(&Pbf[(size_t)n0 * D + lane * 4]));
                    sum.x += x0.x; sum.y += x0.y; sum.z += x0.z; sum.w += x0.w;
                }
                float inv = 1.0f / (float)(me - ms);
                mx.x = fmaxf(mx.x, sum.x * inv); mx.y = fmaxf(mx.y, sum.y * inv);
                mx.z = fmaxf(mx.z, sum.z * inv); mx.w = fmaxf(mx.w, sum.w * inv);
            }
            second = mx;
        }
        second.x = fmaxf(second.x, 0.f); second.y = fmaxf(second.y, 0.f);
        second.z = fmaxf(second.z, 0.f); second.w = fmaxf(second.w, 0.f);
        *reinterpret_cast<float4*>(&out[(size_t)v * (2 * D) + D + lane * 4]) = second;
    }
}

extern "C" void kernel_launch(void* const* d_in, const int* in_sizes, int n_in,
                              void* d_out, int out_size, void* d_ws, size_t ws_size,
                              hipStream_t stream) {
    const int*   edge_index   = (const int*)d_in[0];
    const float* X            = (const float*)d_in[1];
    const int*   member_nodes = (const int*)d_in[2];
    const int*   comm_ids     = (const int*)d_in[3];
    const int*   comm_owner   = (const int*)d_in[4];

    const int nnz_e = in_sizes[0] / 2;
    const int M     = in_sizes[2];
    const int C     = in_sizes[4];

    int* ws = (int*)d_ws;
    int off = 0;
    int*   deg    = ws + off; off += N;
    int*   ell    = ws + off; off += N * KMAX;
    off = (off + 3) & ~3;                        // 16B align
    unsigned short* xbf  = (unsigned short*)(ws + off); off += ND / 2;  // bf16 X (2 MB)
    unsigned short* y1bf = (unsigned short*)(ws + off); off += ND / 2;  // bf16 y1 (2 MB)
    unsigned short* pbf  = (unsigned short*)(ws + off); off += ND / 2;  // bf16 prop (2 MB)
    int*   start  = ws + off; off += C + 1;
    int*   ostart = ws + off; off += N + 1;

    const int* row = edge_index;
    const int* col = edge_index + nnz_e;
    float* outp = (float*)d_out;

    k_pre<<<2048, 256, 0, stream>>>(deg, X, xbf);

    int maxt = nnz_e;
    if (C + 1 > maxt) maxt = C + 1;
    if (N + 1 > maxt) maxt = N + 1;
    k_build<<<(maxt + 255) / 256, 256, 0, stream>>>(
        row, col, nnz_e, deg, ell, comm_ids, M, C, start, comm_owner, ostart);

    k_spmm1<<<ROW_BLOCKS, 256, 0, stream>>>(deg, ell, xbf, y1bf);
    k_spmm2<<<ROW_BLOCKS, 256, 0, stream>>>(deg, ell, y1bf, pbf, outp);
    k_owner<<<N, 256, 0, stream>>>(member_nodes, start, ostart, pbf, outp);
}

// Round 14
// 42.044 us; speedup vs baseline: 1.5043x; 1.0721x over previous
//
#include <hip/hip_runtime.h>
#include <math.h>

constexpr int N = 4096;
constexpr int D = 256;
constexpr int ND = N * D;
constexpr int KMAX = 32;             // safe bound on directed degree (Poisson(~6))
constexpr int ROW_BLOCKS = N / 4;    // 4 waves (rows) per 256-thread block

// ---- bf16 helpers (RNE) ----
__device__ inline unsigned short f2bf(float f) {
    unsigned u = __float_as_uint(f);
    unsigned r = (u + 0x7FFFu + ((u >> 16) & 1u)) >> 16;
    return (unsigned short)r;
}
__device__ inline float bf2f(unsigned short h) {
    return __uint_as_float(((unsigned)h) << 16);
}
__device__ inline float4 bf4_to_f4(ushort4 s) {
    return make_float4(bf2f(s.x), bf2f(s.y), bf2f(s.z), bf2f(s.w));
}
__device__ inline ushort4 f4_to_bf4(float4 f) {
    ushort4 s; s.x = f2bf(f.x); s.y = f2bf(f.y); s.z = f2bf(f.z); s.w = f2bf(f.w);
    return s;
}

__device__ inline int lower_bound(const int* __restrict__ a, int n, int key) {
    int lo = 0, hi = n;
    while (lo < hi) {
        int mid = (lo + hi) >> 1;
        if (a[mid] < key) lo = mid + 1; else hi = mid;
    }
    return lo;
}

// 64-lane ascending bitonic sort (int keys). Lanes hold one key each.
__device__ inline int wave_sort_asc(int v, int lane) {
    for (int k = 2; k <= 64; k <<= 1) {
        for (int j = k >> 1; j >= 1; j >>= 1) {
            int other = __shfl_xor(v, j);
            bool up = ((lane & k) == 0);          // ascending region of this merge
            bool hi = ((lane & j) != 0);          // upper partner of the pair
            bool keepMax = (hi == up);
            int mn = v < other ? v : other;
            int mx = v > other ? v : other;
            v = keepMax ? mx : mn;
        }
    }
    return v;
}

// ---------------- K1: zero deg + segment-bound binary searches ----------------
__global__ __launch_bounds__(256) void k_pre(int* __restrict__ deg,
                                             const int* __restrict__ comm_ids, int M, int C,
                                             int* __restrict__ start,
                                             const int* __restrict__ comm_owner,
                                             int* __restrict__ ostart) {
    int t = blockIdx.x * blockDim.x + threadIdx.x;
    if (t < N) deg[t] = 0;
    if (t <= C) start[t] = lower_bound(comm_ids, M, t);
    if (t <= N) ostart[t] = lower_bound(comm_owner, C, t);
}

// ---------------- K2: ELL build (atomic slot scatter; order canonicalized later) ----------------
__global__ void k_build(const int* __restrict__ row, const int* __restrict__ col,
                        int nnz_e, int* __restrict__ deg, int* __restrict__ ell) {
    int t = blockIdx.x * blockDim.x + threadIdx.x;
    if (t < nnz_e) {
        int r = row[t], c = col[t];
        int pos = atomicAdd(&deg[r], 1);
        if (pos < KMAX) ell[r * KMAX + pos] = c;
    }
}

// ---------------- K3: SpMM pass 1 (f32 X -> bf16 y1), canonicalizing ELL ----------------
// Sorts the row's neighbor list across lanes (deterministic multiset order),
// writes it back so every later consumer sees a bit-deterministic ELL.
__global__ __launch_bounds__(256) void k_spmm1(const int* __restrict__ deg,
                                               int* __restrict__ ell,
                                               const float* __restrict__ X,
                                               unsigned short* __restrict__ Ybf) {
    int r = blockIdx.x * 4 + (threadIdx.x >> 6);
    int lane = threadIdx.x & 63;
    int dcnt = deg[r];
    int cnt = dcnt > KMAX ? KMAX : dcnt;
    float dr = rsqrtf((float)dcnt + 1.0f);

    // load + canonical sort + writeback
    int c_raw = (lane < cnt) ? ell[r * KMAX + lane] : 0x7FFFFFFF;
    int c_s = wave_sort_asc(c_raw, lane);
    if (lane < cnt) ell[r * KMAX + lane] = c_s;

    const float4 xs = *reinterpret_cast<const float4*>(&X[(size_t)r * D + lane * 4]);
    float w0 = dr * dr;              // implicit self loop
    float4 acc0, acc1;
    acc0.x = w0 * xs.x; acc0.y = w0 * xs.y; acc0.z = w0 * xs.z; acc0.w = w0 * xs.w;
    acc1.x = 0.f; acc1.y = 0.f; acc1.z = 0.f; acc1.w = 0.f;

    int   c_l = 0;
    float w_l = 0.0f;
    if (lane < cnt) {
        c_l = c_s;
        w_l = dr * rsqrtf((float)deg[c_l] + 1.0f);
    }
    int k = 0;
    for (; k + 1 < cnt; k += 2) {
        int   c0 = __shfl(c_l, k),  c1 = __shfl(c_l, k + 1);
        float u0 = __shfl(w_l, k),  u1 = __shfl(w_l, k + 1);
        const float4 x0 = *reinterpret_cast<const float4*>(&X[(size_t)c0 * D + lane * 4]);
        const float4 x1 = *reinterpret_cast<const float4*>(&X[(size_t)c1 * D + lane * 4]);
        acc0.x += u0 * x0.x; acc0.y += u0 * x0.y; acc0.z += u0 * x0.z; acc0.w += u0 * x0.w;
        acc1.x += u1 * x1.x; acc1.y += u1 * x1.y; acc1.z += u1 * x1.z; acc1.w += u1 * x1.w;
    }
    if (k < cnt) {
        int   c0 = __shfl(c_l, k);
        float u0 = __shfl(w_l, k);
        const float4 x0 = *reinterpret_cast<const float4*>(&X[(size_t)c0 * D + lane * 4]);
        acc0.x += u0 * x0.x; acc0.y += u0 * x0.y; acc0.z += u0 * x0.z; acc0.w += u0 * x0.w;
    }
    acc0.x += acc1.x; acc0.y += acc1.y; acc0.z += acc1.z; acc0.w += acc1.w;
    *reinterpret_cast<ushort4*>(&Ybf[(size_t)r * D + lane * 4]) = f4_to_bf4(acc0);
}

// ---------------- K4: SpMM pass 2 (sorted ELL): bf16 y1 -> bf16 prop + relu first half ----------------
__global__ __launch_bounds__(256) void k_spmm2(const int* __restrict__ deg,
                                               const int* __restrict__ ell,
                                               const unsigned short* __restrict__ Ybf,
                                               unsigned short* __restrict__ Pbf,
                                               float* __restrict__ OUT) {
    int r = blockIdx.x * 4 + (threadIdx.x >> 6);
    int lane = threadIdx.x & 63;
    int dcnt = deg[r];
    int cnt = dcnt > KMAX ? KMAX : dcnt;
    float dr = rsqrtf((float)dcnt + 1.0f);

    const float4 xs = bf4_to_f4(*reinterpret_cast<const ushort4*>(&Ybf[(size_t)r * D + lane * 4]));
    float w0 = dr * dr;              // implicit self loop
    float4 acc0, acc1;
    acc0.x = w0 * xs.x; acc0.y = w0 * xs.y; acc0.z = w0 * xs.z; acc0.w = w0 * xs.w;
    acc1.x = 0.f; acc1.y = 0.f; acc1.z = 0.f; acc1.w = 0.f;

    int   c_l = 0;
    float w_l = 0.0f;
    if (lane < cnt) {
        c_l = ell[r * KMAX + lane];      // sorted by k_spmm1 -> deterministic order
        w_l = dr * rsqrtf((float)deg[c_l] + 1.0f);
    }
    int k = 0;
    for (; k + 1 < cnt; k += 2) {
        int   c0 = __shfl(c_l, k),  c1 = __shfl(c_l, k + 1);
        float u0 = __shfl(w_l, k),  u1 = __shfl(w_l, k + 1);
        const float4 x0 = bf4_to_f4(*reinterpret_cast<const ushort4*>(&Ybf[(size_t)c0 * D + lane * 4]));
        const float4 x1 = bf4_to_f4(*reinterpret_cast<const ushort4*>(&Ybf[(size_t)c1 * D + lane * 4]));
        acc0.x += u0 * x0.x; acc0.y += u0 * x0.y; acc0.z += u0 * x0.z; acc0.w += u0 * x0.w;
        acc1.x += u1 * x1.x; acc1.y += u1 * x1.y; acc1.z += u1 * x1.z; acc1.w += u1 * x1.w;
    }
    if (k < cnt) {
        int   c0 = __shfl(c_l, k);
        float u0 = __shfl(w_l, k);
        const float4 x0 = bf4_to_f4(*reinterpret_cast<const ushort4*>(&Ybf[(size_t)c0 * D + lane * 4]));
        acc0.x += u0 * x0.x; acc0.y += u0 * x0.y; acc0.z += u0 * x0.z; acc0.w += u0 * x0.w;
    }
    acc0.x += acc1.x; acc0.y += acc1.y; acc0.z += acc1.z; acc0.w += acc1.w;

    *reinterpret_cast<ushort4*>(&Pbf[(size_t)r * D + lane * 4]) = f4_to_bf4(acc0);
    float4 f;
    f.x = fmaxf(acc0.x, 0.f); f.y = fmaxf(acc0.y, 0.f);
    f.z = fmaxf(acc0.z, 0.f); f.w = fmaxf(acc0.w, 0.f);
    *reinterpret_cast<float4*>(&OUT[(size_t)r * (2 * D) + lane * 4]) = f;
}

// ---------------- K5: community mean (single comm per owner) -> out second half ----------------
__global__ __launch_bounds__(256) void k_owner(const int* __restrict__ member_nodes,
                                               const int* __restrict__ start,
                                               const int* __restrict__ ostart,
                                               const unsigned short* __restrict__ Pbf,
                                               float* __restrict__ out) {
    __shared__ float4 part[4][64];
    int wave = threadIdx.x >> 6;         // 0..3 : which quarter of the member list
    int lane = threadIdx.x & 63;
    int v = blockIdx.x;
    int cs = ostart[v], ce = ostart[v + 1];
    int single = (ce - cs == 1);

    float4 a0 = make_float4(0.f, 0.f, 0.f, 0.f);
    float4 a1 = a0, a2 = a0, a3 = a0;
    int cnt = 0;
    if (single) {
        int ms = start[cs], me = start[cs + 1];
        cnt = me - ms;
        int nh = cnt > wave ? ((cnt - wave + 3) >> 2) : 0;   // members at ms+wave+4*j
        for (int base = 0; base < nh; base += 64) {
            int j = base + lane;
            int id_l = 0;
            if (j < nh) id_l = member_nodes[ms + wave + 4 * j];
            int kmax = nh - base; if (kmax > 64) kmax = 64;
            int k = 0;
            for (; k + 3 < kmax; k += 4) {
                int n0 = __shfl(id_l, k),     n1 = __shfl(id_l, k + 1);
                int n2 = __shfl(id_l, k + 2), n3 = __shfl(id_l, k + 3);
                const float4 x0 = bf4_to_f4(*reinterpret_cast<const ushort4*>(&Pbf[(size_t)n0 * D + lane * 4]));
                const float4 x1 = bf4_to_f4(*reinterpret_cast<const ushort4*>(&Pbf[(size_t)n1 * D + lane * 4]));
                const float4 x2 = bf4_to_f4(*reinterpret_cast<const ushort4*>(&Pbf[(size_t)n2 * D + lane * 4]));
                const float4 x3 = bf4_to_f4(*reinterpret_cast<const ushort4*>(&Pbf[(size_t)n3 * D + lane * 4]));
                a0.x += x0.x; a0.y += x0.y; a0.z += x0.z; a0.w += x0.w;
                a1.x += x1.x; a1.y += x1.y; a1.z += x1.z; a1.w += x1.w;
                a2.x += x2.x; a2.y += x2.y; a2.z += x2.z; a2.w += x2.w;
                a3.x += x3.x; a3.y += x3.y; a3.z += x3.z; a3.w += x3.w;
            }
            for (; k < kmax; ++k) {
                int n0 = __shfl(id_l, k);
                const float4 x0 = bf4_to_f4(*reinterpret_cast<const ushort4*>(&Pbf[(size_t)n0 * D + lane * 4]));
                a0.x += x0.x; a0.y += x0.y; a0.z += x0.z; a0.w += x0.w;
            }
        }
        a0.x += a1.x + a2.x + a3.x;
        a0.y += a1.y + a2.y + a3.y;
        a0.z += a1.z + a2.z + a3.z;
        a0.w += a1.w + a2.w + a3.w;
    }
    part[wave][lane] = a0;
    __syncthreads();                      // uniform barrier

    if (wave == 0) {
        float4 second;
        if (single) {
            float4 p1 = part[1][lane], p2 = part[2][lane], p3 = part[3][lane];
            float inv = 1.0f / (float)cnt;
            second.x = (a0.x + p1.x + p2.x + p3.x) * inv;
            second.y = (a0.y + p1.y + p2.y + p3.y) * inv;
            second.z = (a0.z + p1.z + p2.z + p3.z) * inv;
            second.w = (a0.w + p1.w + p2.w + p3.w) * inv;
        } else if (cs == ce) {
            second = bf4_to_f4(*reinterpret_cast<const ushort4*>(&Pbf[(size_t)v * D + lane * 4]));
        } else {
            // general multi-community path (dead on this data, kept for safety)
            float4 mx = make_float4(-INFINITY, -INFINITY, -INFINITY, -INFINITY);
            for (int c = cs; c < ce; ++c) {
                int ms = start[c], me = start[c + 1];
                float4 sum = make_float4(0.f, 0.f, 0.f, 0.f);
                for (int m = ms; m < me; ++m) {
                    int n0 = member_nodes[m];
                    const float4 x0 = bf4_to_f4(*reinterpret_cast<const ushort4*>(&Pbf[(size_t)n0 * D + lane * 4]));
                    sum.x += x0.x; sum.y += x0.y; sum.z += x0.z; sum.w += x0.w;
                }
                float inv = 1.0f / (float)(me - ms);
                mx.x = fmaxf(mx.x, sum.x * inv); mx.y = fmaxf(mx.y, sum.y * inv);
                mx.z = fmaxf(mx.z, sum.z * inv); mx.w = fmaxf(mx.w, sum.w * inv);
            }
            second = mx;
        }
        second.x = fmaxf(second.x, 0.f); second.y = fmaxf(second.y, 0.f);
        second.z = fmaxf(second.z, 0.f); second.w = fmaxf(second.w, 0.f);
        *reinterpret_cast<float4*>(&out[(size_t)v * (2 * D) + D + lane * 4]) = second;
    }
}

extern "C" void kernel_launch(void* const* d_in, const int* in_sizes, int n_in,
                              void* d_out, int out_size, void* d_ws, size_t ws_size,
                              hipStream_t stream) {
    const int*   edge_index   = (const int*)d_in[0];
    const float* X            = (const float*)d_in[1];
    const int*   member_nodes = (const int*)d_in[2];
    const int*   comm_ids     = (const int*)d_in[3];
    const int*   comm_owner   = (const int*)d_in[4];

    const int nnz_e = in_sizes[0] / 2;
    const int M     = in_sizes[2];
    const int C     = in_sizes[4];

    int* ws = (int*)d_ws;
    int off = 0;
    int*   deg    = ws + off; off += N;
    int*   ell    = ws + off; off += N * KMAX;
    off = (off + 3) & ~3;                        // 16B align
    unsigned short* y1bf = (unsigned short*)(ws + off); off += ND / 2;  // bf16 y1 (2 MB)
    unsigned short* pbf  = (unsigned short*)(ws + off); off += ND / 2;  // bf16 prop (2 MB)
    int*   start  = ws + off; off += C + 1;
    int*   ostart = ws + off; off += N + 1;

    const int* row = edge_index;
    const int* col = edge_index + nnz_e;
    float* outp = (float*)d_out;

    int pre_threads = (C > N ? C : N) + 1;
    k_pre<<<(pre_threads + 255) / 256, 256, 0, stream>>>(deg, comm_ids, M, C, start,
                                                         comm_owner, ostart);
    k_build<<<(nnz_e + 255) / 256, 256, 0, stream>>>(row, col, nnz_e, deg, ell);
    k_spmm1<<<ROW_BLOCKS, 256, 0, stream>>>(deg, ell, X, y1bf);
    k_spmm2<<<ROW_BLOCKS, 256, 0, stream>>>(deg, ell, y1bf, pbf, outp);
    k_owner<<<N, 256, 0, stream>>>(member_nodes, start, ostart, pbf, outp);
}